// Round 11
// baseline (28044.296 us; speedup 1.0000x reference)
//
#include <hip/hip_runtime.h>
#include <math.h>

// Round 11: conv3x3 v6 = R9's proven 4px x 4oc / 64oc-tile structure +
// double-buffered LDS with register prefetch (T14 async-STAGE, plain HIP).
// Staging addresses are affine in ic0 -> per-slot constants precomputed once;
// per step: issue NEXT tile's global loads -> compute CURRENT buffer ->
// write regs -> other buffer -> single barrier. Staged values / LDS layout /
// FMA order identical to R9 -> z bit-exact.
// Anchors (frozen): fp32 encoder, fp32 op-order epilogue, VQ numpy-fp32 grid
// emulation with first-index argmin. convt/dow/conv0/conv1x1/host = R9.

static constexpr float kBNF = 0.9999950000374997f;

// ---------------------------------------------------------------- conv0: 1->128, 3x3, s1, relu (B=1), fp32
__global__ __launch_bounds__(320) void conv0_k(const float* __restrict__ x,
                                               const float* __restrict__ w,
                                               const float* __restrict__ b,
                                               float* __restrict__ out) {
  const int H = 320, W = 320, OC = 128;
  int oy = blockIdx.x;
  int tx = threadIdx.x;
  __shared__ float in_s[3][W + 2];
  __shared__ float w_s[128 * 9];
  __shared__ float b_s[128];
  for (int e = tx; e < 3 * (W + 2); e += 320) {
    int r = e / (W + 2), c = e % (W + 2);
    int iy = oy + r - 1, ix = c - 1;
    float v = 0.f;
    if (iy >= 0 && iy < H && ix >= 0 && ix < W) v = x[iy * W + ix];
    in_s[r][c] = v;
  }
  for (int e = tx; e < 128 * 9; e += 320) w_s[e] = w[e];
  for (int e = tx; e < 128; e += 320) b_s[e] = b[e];
  __syncthreads();
  float iv[9];
#pragma unroll
  for (int r = 0; r < 3; ++r)
#pragma unroll
    for (int c = 0; c < 3; ++c) iv[r * 3 + c] = in_s[r][tx + c];
  for (int oc = 0; oc < OC; ++oc) {
    float acc = 0.f;
#pragma unroll
    for (int t = 0; t < 9; ++t) acc = fmaf(w_s[oc * 9 + t], iv[t], acc);
    float v32 = __fadd_rn(acc, b_s[oc]);
    v32 = __fmul_rn(v32, kBNF);
    out[(oc * H + oy) * W + tx] = fmaxf(v32, 0.f);
  }
}

// ---------------------------------------------------------------- 3x3 conv v6: dbuf + reg prefetch
template <int S, bool RELU, bool HAS_SKIP>
__global__ __launch_bounds__(256) void conv3x3_k(
    const float* __restrict__ in, const float* __restrict__ w,
    const float* __restrict__ bias, const float* __restrict__ skip,
    float* __restrict__ out, int IC, int IH, int IW, int OC, int OH, int OW) {
  const int NCOL = 64 * S + 2;              // 66 or 130
  const int ROWL = (S == 1) ? 68 : 136;     // LDS row floats
  const int NIN = 4 * 3 * NCOL;             // 792 or 1560
  const int NSI = (S == 1) ? 4 : 7;         // ceil(NIN/256)
  __shared__ float in_f[2][4][3][(S == 1) ? 68 : 136];
  __shared__ float w_f[2][4][9][64];
  int t = threadIdx.x;
  int ox0 = blockIdx.x * 64;
  int oy = blockIdx.y;
  int oc0 = blockIdx.z * 64;
  int oc4 = (t >> 4) * 4, px4 = (t & 15) * 4;
  const int IHW = IH * IW;

  // --- per-slot constants (affine in ic0), computed ONCE
  int ibase[NSI], ilofs[NSI];
  bool iuse[NSI], ival[NSI];
#pragma unroll
  for (int j = 0; j < NSI; ++j) {
    int e = t + 256 * j;
    iuse[j] = (e < NIN);
    int ee = iuse[j] ? e : 0;
    int icr = ee / (3 * NCOL);
    int rem = ee - icr * (3 * NCOL);
    int r = rem / NCOL, c = rem - r * NCOL;
    int iy = oy * S - 1 + r;
    int ix = ox0 * S - 1 + c;
    ival[j] = iuse[j] && iy >= 0 && iy < IH && ix >= 0 && ix < IW;
    ibase[j] = (icr * IH + iy) * IW + ix;
    ilofs[j] = (S == 1) ? (icr * 3 + r) * ROWL + c
                        : (icr * 3 + r) * ROWL + (c & 1) * 68 + (c >> 1);
  }
  int wbase[9], wlofs[9];
#pragma unroll
  for (int j = 0; j < 9; ++j) {
    int e = t + 256 * j;
    int ocr = e & 63;
    int rem = e >> 6;
    int tap = rem % 9, icr = rem / 9;
    wbase[j] = ((oc0 + ocr) * IC + icr) * 9 + tap;
    wlofs[j] = (icr * 9 + tap) * 64 + ocr;
  }

  // --- prologue: stage ic0=0 into buffer 0 (values identical to R9 staging)
  {
    float* ib = &in_f[0][0][0][0];
    float* wb = &w_f[0][0][0][0];
#pragma unroll
    for (int j = 0; j < NSI; ++j)
      if (iuse[j]) ib[ilofs[j]] = ival[j] ? in[ibase[j]] : 0.f;
#pragma unroll
    for (int j = 0; j < 9; ++j) wb[wlofs[j]] = w[wbase[j]];
  }

  float acc[4][4] = {};
  const int nstep = IC >> 2;
  for (int step = 0; step < nstep; ++step) {
    __syncthreads();
    const int cur = step & 1;
    const bool more = (step + 1 < nstep);
    float rIn[NSI], rW[9];
    if (more) {
      const int icoff = (step + 1) * 4 * IHW;
#pragma unroll
      for (int j = 0; j < NSI; ++j)
        rIn[j] = ival[j] ? in[ibase[j] + icoff] : 0.f;
      const int wcoff = (step + 1) * 4 * 9;
#pragma unroll
      for (int j = 0; j < 9; ++j) rW[j] = w[wbase[j] + wcoff];
    }
    // --- compute current buffer (identical FMA order to R9)
#pragma unroll
    for (int icr = 0; icr < 4; ++icr) {
#pragma unroll
      for (int ky = 0; ky < 3; ++ky) {
        float iv[9];
        if (S == 1) {
          float4 va = *reinterpret_cast<const float4*>(&in_f[cur][icr][ky][px4]);
          float2 vb = *reinterpret_cast<const float2*>(&in_f[cur][icr][ky][px4 + 4]);
          iv[0] = va.x; iv[1] = va.y; iv[2] = va.z;
          iv[3] = va.w; iv[4] = vb.x; iv[5] = vb.y;
        } else {
          float4 ve = *reinterpret_cast<const float4*>(&in_f[cur][icr][ky][px4]);
          float se = in_f[cur][icr][ky][px4 + 4];
          float4 vo = *reinterpret_cast<const float4*>(&in_f[cur][icr][ky][68 + px4]);
          iv[0] = ve.x; iv[1] = ve.y; iv[2] = ve.z;
          iv[3] = ve.w; iv[4] = se;
          iv[5] = vo.x; iv[6] = vo.y; iv[7] = vo.z; iv[8] = vo.w;
        }
#pragma unroll
        for (int kx = 0; kx < 3; ++kx) {
          float4 wv = *reinterpret_cast<const float4*>(&w_f[cur][icr][ky * 3 + kx][oc4]);
          const float* wp = (const float*)&wv;
#pragma unroll
          for (int p = 0; p < 4; ++p) {
            float ivv;
            if (S == 1) {
              ivv = iv[p + kx];
            } else {
              ivv = (kx == 0) ? iv[p] : (kx == 1) ? iv[5 + p] : iv[p + 1];
            }
#pragma unroll
            for (int o = 0; o < 4; ++o)
              acc[o][p] = fmaf(wp[o], ivv, acc[o][p]);
          }
        }
      }
    }
    // --- write prefetched tile to other buffer
    if (more) {
      float* ib = &in_f[cur ^ 1][0][0][0];
      float* wb = &w_f[cur ^ 1][0][0][0];
#pragma unroll
      for (int j = 0; j < NSI; ++j)
        if (iuse[j]) ib[ilofs[j]] = rIn[j];
#pragma unroll
      for (int j = 0; j < 9; ++j) wb[wlofs[j]] = rW[j];
    }
  }
  int opx = ox0 + px4;
  if (opx < OW) {
#pragma unroll
    for (int o = 0; o < 4; ++o) {
      int oc = oc0 + oc4 + o;
      float bv = bias[oc];
      size_t base = ((size_t)oc * OH + oy) * OW + opx;
      float4 rv;
      float* rp = (float*)&rv;
#pragma unroll
      for (int p = 0; p < 4; ++p) {
        float v32 = __fadd_rn(acc[o][p], bv);
        v32 = __fmul_rn(v32, kBNF);
        if (HAS_SKIP) v32 = __fadd_rn(v32, skip[base + p]);
        if (RELU) v32 = fmaxf(v32, 0.f);
        rp[p] = v32;
      }
      *reinterpret_cast<float4*>(&out[base]) = rv;
    }
  }
}

// ---------------------------------------------------------------- 1x1 conv, fp32 acc (R9)
template <int S, bool RELU>
__global__ __launch_bounds__(256) void conv1x1_k(
    const float* __restrict__ in, const float* __restrict__ w,
    const float* __restrict__ bias, float* __restrict__ out,
    int IC, int IH, int IW, int OC, int OH, int OW) {
  __shared__ float in_s[16][64];
  __shared__ float w_s[16][64];
  const int P = OH * OW;
  int t = threadIdx.x;
  int p0 = blockIdx.x * 64;
  int oc0 = blockIdx.y * 64;
  int oc4 = (t >> 4) * 4, px4 = (t & 15) * 4;
  float acc[4][4] = {};
  for (int ic0 = 0; ic0 < IC; ic0 += 16) {
    __syncthreads();
    {
      int e = t;
#pragma unroll
      for (int k = 0; k < 4; ++k, e += 256) {
        int icr = e >> 6, pxr = e & 63;
        int p = p0 + pxr;
        float v = 0.f;
        if (p < P) {
          int oy = p / OW, ox = p % OW;
          v = in[((ic0 + icr) * IH + oy * S) * IW + ox * S];
        }
        in_s[icr][pxr] = v;
      }
      e = t;
#pragma unroll
      for (int k = 0; k < 4; ++k, e += 256) {
        int icr = e >> 6, ocr = e & 63;
        w_s[icr][ocr] = w[(oc0 + ocr) * IC + ic0 + icr];
      }
    }
    __syncthreads();
#pragma unroll
    for (int icr = 0; icr < 16; ++icr) {
      float4 iv = *reinterpret_cast<const float4*>(&in_s[icr][px4]);
      float4 wv = *reinterpret_cast<const float4*>(&w_s[icr][oc4]);
      const float* ip = (const float*)&iv;
      const float* wp = (const float*)&wv;
#pragma unroll
      for (int o = 0; o < 4; ++o)
#pragma unroll
        for (int p = 0; p < 4; ++p)
          acc[o][p] = fmaf(wp[o], ip[p], acc[o][p]);
    }
  }
  int p = p0 + px4;
  if (p < P) {
    int oy = p / OW, ox = p % OW;
#pragma unroll
    for (int o = 0; o < 4; ++o) {
      int oc = oc0 + oc4 + o;
      float bv = bias[oc];
      float4 rv;
      float* rp = (float*)&rv;
#pragma unroll
      for (int pp = 0; pp < 4; ++pp) {
        float v32 = __fadd_rn(acc[o][pp], bv);
        v32 = __fmul_rn(v32, kBNF);
        if (RELU) v32 = fmaxf(v32, 0.f);
        rp[pp] = v32;
      }
      *reinterpret_cast<float4*>(&out[((size_t)oc * OH + oy) * OW + ox]) = rv;
    }
  }
}

// ---------------------------------------------------------------- ConvT weight transpose: w2[kyb][ic][ty][kx][OC]
__global__ __launch_bounds__(256) void prep_w2_k(const float* __restrict__ w,
                                                 float* __restrict__ w2,
                                                 int IC, int OC) {
  int i = blockIdx.x * 256 + threadIdx.x;
  int total = IC * OC * 16;
  if (i >= total) return;
  int oc = i % OC;
  int r = i / OC;
  int kx = r & 3; r >>= 2;
  int ty = r & 1; r >>= 1;
  int ic = r % IC;
  int kyb = r / IC;
  int ky = kyb + 2 * ty;
  w2[i] = w[((size_t)ic * OC + oc) * 16 + ky * 4 + kx];
}

// ---------------------------------------------------------------- ConvTranspose2d k4 s2 p1, relu, ICS=8 (R9)
__global__ __launch_bounds__(256) void convt_k(
    const float* __restrict__ in, const float* __restrict__ w2,
    const float* __restrict__ bias, float* __restrict__ out,
    int IC, int IH, int IW, int OC, int OH, int OW) {
  __shared__ float in_s[8][2][34];
  __shared__ float w_s[8][2][4][64];
  int t = threadIdx.x;
  int ox0 = blockIdx.x * 64;
  int oy = blockIdx.y;
  int oc0 = blockIdx.z * 64;
  int oc4 = (t >> 4) * 4, px4 = (t & 15) * 4;
  int kyb = (oy & 1) ? 0 : 1;
  int c0 = ox0 >> 1;
  const float* w2b = w2 + (size_t)kyb * IC * 8 * OC;  // [ic][ty][kx][OC]
  float acc[4][4] = {};
  for (int ic0 = 0; ic0 < IC; ic0 += 8) {
    __syncthreads();
    for (int e = t; e < 8 * 2 * 34; e += 256) {
      int icr = e / 68;
      int rem = e - icr * 68;
      int ty = rem / 34, cc = rem - ty * 34;
      int ky = kyb + 2 * ty;
      int iy = (oy + 1 - ky) >> 1;
      int ix = c0 - 1 + cc;
      float v = 0.f;
      if (iy >= 0 && iy < IH && ix >= 0 && ix < IW)
        v = in[((ic0 + icr) * IH + iy) * IW + ix];
      in_s[icr][ty][cc] = v;
    }
    {
      int e = t;
#pragma unroll
      for (int k = 0; k < 16; ++k, e += 256) {
        int icr = e >> 9;
        int rem = e & 511;
        int ty = rem >> 8;
        int kx = (rem >> 6) & 3;
        int ocr = rem & 63;
        w_s[icr][ty][kx][ocr] =
            w2b[((((size_t)(ic0 + icr)) * 2 + ty) * 4 + kx) * OC + oc0 + ocr];
      }
    }
    __syncthreads();
#pragma unroll
    for (int icr = 0; icr < 8; ++icr) {
      float4 wv[2][4];
#pragma unroll
      for (int ty = 0; ty < 2; ++ty)
#pragma unroll
        for (int kx = 0; kx < 4; ++kx)
          wv[ty][kx] = *reinterpret_cast<const float4*>(&w_s[icr][ty][kx][oc4]);
#pragma unroll
      for (int p = 0; p < 4; ++p) {
        int hr = (px4 + p) >> 1;
        int kxa = (p & 1) ? 0 : 1;
        int kxb = (p & 1) ? 2 : 3;
        int ca = (p & 1) ? hr + 2 : hr + 1;
        int cb2 = (p & 1) ? hr + 1 : hr;
#pragma unroll
        for (int ty = 0; ty < 2; ++ty) {
          float sa = in_s[icr][ty][ca];
          float sb = in_s[icr][ty][cb2];
          const float* wa = (const float*)&wv[ty][kxa];
          const float* wb = (const float*)&wv[ty][kxb];
#pragma unroll
          for (int o = 0; o < 4; ++o) {
            acc[o][p] = fmaf(wa[o], sa, acc[o][p]);
            acc[o][p] = fmaf(wb[o], sb, acc[o][p]);
          }
        }
      }
    }
  }
  int opx = ox0 + px4;
  if (opx < OW) {
#pragma unroll
    for (int o = 0; o < 4; ++o) {
      int oc = oc0 + oc4 + o;
      float bv = bias[oc];
      float4 rv;
      float* rp = (float*)&rv;
#pragma unroll
      for (int p = 0; p < 4; ++p) {
        float v = (acc[o][p] + bv) * kBNF;
        rp[p] = fmaxf(v, 0.f);
      }
      *reinterpret_cast<float4*>(&out[((size_t)oc * OH + oy) * OW + opx]) = rv;
    }
  }
}

// ---------------------------------------------------------------- final 3x3 conv 128->1 + sigmoid (B=1) (R9)
__global__ __launch_bounds__(320) void dow_k(const float* __restrict__ in,
                                             const float* __restrict__ w,
                                             const float* __restrict__ bias,
                                             float* __restrict__ out) {
  const int H = 320, W = 320, IC = 128;
  int oy = blockIdx.x;
  int tx = threadIdx.x;
  __shared__ float in_s[4][3][W + 2];
  __shared__ float w_s[IC * 9];
  for (int e = tx; e < IC * 9; e += 320) w_s[e] = w[e];
  float acc = 0.f;
  for (int ic0 = 0; ic0 < IC; ic0 += 4) {
    __syncthreads();
    for (int e = tx; e < 4 * 3 * (W + 2); e += 320) {
      int icr = e / (3 * (W + 2));
      int rem = e - icr * (3 * (W + 2));
      int r = rem / (W + 2), c = rem - r * (W + 2);
      int iy = oy + r - 1, ix = c - 1;
      float v = 0.f;
      if (iy >= 0 && iy < H && ix >= 0 && ix < W)
        v = in[((ic0 + icr) * H + iy) * W + ix];
      in_s[icr][r][c] = v;
    }
    __syncthreads();
#pragma unroll
    for (int icr = 0; icr < 4; ++icr)
#pragma unroll
      for (int r = 0; r < 3; ++r)
#pragma unroll
        for (int c = 0; c < 3; ++c)
          acc = fmaf(w_s[(ic0 + icr) * 9 + r * 3 + c], in_s[icr][r][tx + c], acc);
  }
  acc += bias[0];
  out[oy * W + tx] = 1.f / (1.f + expf(-acc));
}

// ---------------------------------------------------------------- codebook sq-norms: numpy-pairwise fp32
__global__ __launch_bounds__(256) void cbprep_np(const float* __restrict__ cb,
                                                 float* __restrict__ c2f) {
  int e = blockIdx.x, t = threadIdx.x;
  __shared__ float a[256];
  a[t] = cb[e * 256 + t];
  __syncthreads();
  if (t == 0) {
    float tot = 0.f;
    for (int h = 0; h < 2; ++h) {
      const float* p = a + h * 128;
      float r[8];
#pragma unroll
      for (int j = 0; j < 8; ++j) r[j] = __fmul_rn(p[j], p[j]);
      for (int i = 8; i < 128; i += 8)
#pragma unroll
        for (int j = 0; j < 8; ++j) r[j] = __fadd_rn(r[j], __fmul_rn(p[i + j], p[i + j]));
      float s = __fadd_rn(__fadd_rn(__fadd_rn(r[0], r[1]), __fadd_rn(r[2], r[3])),
                          __fadd_rn(__fadd_rn(r[4], r[5]), __fadd_rn(r[6], r[7])));
      tot = (h == 0) ? s : __fadd_rn(tot, s);
    }
    c2f[e] = tot;
  }
}

// ---------------------------------------------------------------- VQ: block-per-row, emulated fp32 ref dist (UNCHANGED)
__global__ __launch_bounds__(256) void vq_ref_k(const float* __restrict__ z,
                                                const float* __restrict__ cb,
                                                const float* __restrict__ c2f,
                                                float* __restrict__ zq_out,
                                                float* __restrict__ idx_out) {
  int row = blockIdx.x;
  int t = threadIdx.x;
  __shared__ float f[256];
  __shared__ float dist[1024];
  __shared__ float f2s;
  __shared__ int bestIdx;
  f[t] = z[(size_t)row * 256 + t];
  __syncthreads();
  if (t == 0) {
    float tot = 0.f;
    for (int h = 0; h < 2; ++h) {
      const float* p = f + h * 128;
      float r[8];
#pragma unroll
      for (int j = 0; j < 8; ++j) r[j] = __fmul_rn(p[j], p[j]);
      for (int i = 8; i < 128; i += 8)
#pragma unroll
        for (int j = 0; j < 8; ++j) r[j] = __fadd_rn(r[j], __fmul_rn(p[i + j], p[i + j]));
      float s = __fadd_rn(__fadd_rn(__fadd_rn(r[0], r[1]), __fadd_rn(r[2], r[3])),
                          __fadd_rn(__fadd_rn(r[4], r[5]), __fadd_rn(r[6], r[7])));
      tot = (h == 0) ? s : __fadd_rn(tot, s);
    }
    f2s = tot;
  }
  __syncthreads();
  float f2 = f2s;
  for (int e = t; e < 1024; e += 256) {
    const float* cbe = cb + (size_t)e * 256;
    double dot = 0.0;
    for (int d = 0; d < 256; ++d)
      dot = fma((double)f[d], (double)cbe[d], dot);
    float C = __fmul_rn(2.f, (float)dot);
    dist[e] = __fsub_rn(__fadd_rn(f2, c2f[e]), C);
  }
  __syncthreads();
  if (t == 0) {
    float bv = dist[0];
    int bi = 0;
    for (int e = 1; e < 1024; ++e)
      if (dist[e] < bv) { bv = dist[e]; bi = e; }
    bestIdx = bi;
    idx_out[row] = (float)bi;
  }
  __syncthreads();
  zq_out[(size_t)row * 256 + t] = cb[(size_t)bestIdx * 256 + t];
}

// ================================================================ host
extern "C" void kernel_launch(void* const* d_in, const int* in_sizes, int n_in,
                              void* d_out, int out_size, void* d_ws, size_t ws_size,
                              hipStream_t stream) {
  const float* x = (const float*)d_in[0];
  const float* w0 = (const float*)d_in[1];
  const float* b0 = (const float*)d_in[2];
  const float* a_c1w = (const float*)d_in[3];
  const float* a_c1b = (const float*)d_in[4];
  const float* a_c2w = (const float*)d_in[5];
  const float* a_c2b = (const float*)d_in[6];
  const float* a_scw = (const float*)d_in[7];
  const float* a_scb = (const float*)d_in[8];
  const float* b_c1w = (const float*)d_in[9];
  const float* b_c1b = (const float*)d_in[10];
  const float* b_c2w = (const float*)d_in[11];
  const float* b_c2b = (const float*)d_in[12];
  const float* b_scw = (const float*)d_in[13];
  const float* b_scb = (const float*)d_in[14];
  const float* ew = (const float*)d_in[15];
  const float* eb = (const float*)d_in[16];
  const float* cb = (const float*)d_in[17];
  const float* d0w = (const float*)d_in[18];
  const float* d0b = (const float*)d_in[19];
  const float* dt1w = (const float*)d_in[20];
  const float* dt1b = (const float*)d_in[21];
  const float* dt2w = (const float*)d_in[22];
  const float* dt2b = (const float*)d_in[23];
  const float* doww = (const float*)d_in[24];
  const float* dob = (const float*)d_in[25];

  // ws (floats): A 13.1M | B 6.55M | C 6.55M | c2f 1024  ~= 105 MB (unchanged)
  float* ws = (float*)d_ws;
  float* A = ws;
  float* Bf = ws + 13107200;
  float* Cf = ws + 19660800;
  float* c2f = ws + 26214400;
  float* w2dt1 = A;              // dead region during decoder
  float* w2dt2 = Bf + 3400000;   // past g0's 3.28M floats

  float* outf = (float*)d_out;
  float* recon = outf;
  float* zq = outf + 409600;
  float* idxo = zq + 6553600;

  cbprep_np<<<1024, 256, 0, stream>>>(cb, c2f);

  for (int b = 0; b < 4; ++b) {
    const float* xb = x + (size_t)b * 102400;
    float* zqb = zq + (size_t)b * 1638400;
    float* idxb = idxo + (size_t)b * 6400;
    float* reconb = recon + (size_t)b * 102400;

    // encoder (fp32; staged values + FMA order identical -> z bit-identical)
    conv0_k<<<320, 320, 0, stream>>>(xb, w0, b0, A);
    conv3x3_k<2, true, false><<<dim3(3, 160, 4), 256, 0, stream>>>(
        A, a_c1w, a_c1b, nullptr, Bf, 128, 320, 320, 256, 160, 160);
    conv1x1_k<2, false><<<dim3(400, 4), 256, 0, stream>>>(
        A, a_scw, a_scb, Cf, 128, 320, 320, 256, 160, 160);
    conv3x3_k<1, true, true><<<dim3(3, 160, 4), 256, 0, stream>>>(
        Bf, a_c2w, a_c2b, Cf, A, 256, 160, 160, 256, 160, 160);
    conv3x3_k<2, true, false><<<dim3(2, 80, 8), 256, 0, stream>>>(
        A, b_c1w, b_c1b, nullptr, Bf, 256, 160, 160, 512, 80, 80);
    conv1x1_k<2, false><<<dim3(100, 8), 256, 0, stream>>>(
        A, b_scw, b_scb, Cf, 256, 160, 160, 512, 80, 80);
    conv3x3_k<1, true, true><<<dim3(2, 80, 8), 256, 0, stream>>>(
        Bf, b_c2w, b_c2b, Cf, A, 512, 80, 80, 512, 80, 80);
    conv1x1_k<1, false><<<dim3(100, 4), 256, 0, stream>>>(
        A, ew, eb, Cf, 512, 80, 80, 256, 80, 80);
    // VQ (unchanged emulation)
    vq_ref_k<<<6400, 256, 0, stream>>>(Cf, cb, c2f, zqb, idxb);
    // decoder
    prep_w2_k<<<8192, 256, 0, stream>>>(dt1w, w2dt1, 512, 256);
    prep_w2_k<<<2048, 256, 0, stream>>>(dt2w, w2dt2, 256, 128);
    conv1x1_k<1, true><<<dim3(100, 8), 256, 0, stream>>>(
        zqb, d0w, d0b, Bf, 256, 80, 80, 512, 80, 80);
    convt_k<<<dim3(3, 160, 4), 256, 0, stream>>>(
        Bf, w2dt1, dt1b, Cf, 512, 80, 80, 256, 160, 160);
    convt_k<<<dim3(5, 320, 2), 256, 0, stream>>>(
        Cf, w2dt2, dt2b, A, 256, 160, 160, 128, 320, 320);
    dow_k<<<320, 320, 0, stream>>>(A, doww, dob, reconb);
  }
}

// Round 12
// 20000.027 us; speedup vs baseline: 1.4022x; 1.4022x over previous
//
#include <hip/hip_runtime.h>
#include <math.h>

// Round 12: R9 baseline (best passing, 20.45 ms) + ONE change: conv3x3 weights
// pre-transposed per layer to [ic][tap][OC] so staging is coalesced (was
// lane-stride IC*9 -> 64 cache lines per wave instruction). Staged values, LDS
// layout, FMA order identical -> z bit-exact.
// Anchors (frozen): fp32 encoder, fp32 op-order epilogue, VQ numpy-fp32 grid
// emulation with first-index argmin.
// w2 placements (all within proven 106 MB ws footprint):
//   a_c1 -> Cf        (dead until a_sc writes it; prep before a_c1)
//   a_c2 -> A+6.6M    (h0 dead after a_c1+a_sc; clear of a_c2 out [0..6.55M))
//   b_c1 -> Bf+3.3M   (a_c1-out dead after a_c2; clear of b_c1 out [0..3.28M))
//   b_c2 -> A+3.3M    (a_out dead after b_c1+b_sc; clear of b_c2 out)

static constexpr float kBNF = 0.9999950000374997f;

// ---------------------------------------------------------------- conv0: 1->128, 3x3, s1, relu (B=1), fp32
__global__ __launch_bounds__(320) void conv0_k(const float* __restrict__ x,
                                               const float* __restrict__ w,
                                               const float* __restrict__ b,
                                               float* __restrict__ out) {
  const int H = 320, W = 320, OC = 128;
  int oy = blockIdx.x;
  int tx = threadIdx.x;
  __shared__ float in_s[3][W + 2];
  __shared__ float w_s[128 * 9];
  __shared__ float b_s[128];
  for (int e = tx; e < 3 * (W + 2); e += 320) {
    int r = e / (W + 2), c = e % (W + 2);
    int iy = oy + r - 1, ix = c - 1;
    float v = 0.f;
    if (iy >= 0 && iy < H && ix >= 0 && ix < W) v = x[iy * W + ix];
    in_s[r][c] = v;
  }
  for (int e = tx; e < 128 * 9; e += 320) w_s[e] = w[e];
  for (int e = tx; e < 128; e += 320) b_s[e] = b[e];
  __syncthreads();
  float iv[9];
#pragma unroll
  for (int r = 0; r < 3; ++r)
#pragma unroll
    for (int c = 0; c < 3; ++c) iv[r * 3 + c] = in_s[r][tx + c];
  for (int oc = 0; oc < OC; ++oc) {
    float acc = 0.f;
#pragma unroll
    for (int t = 0; t < 9; ++t) acc = fmaf(w_s[oc * 9 + t], iv[t], acc);
    float v32 = __fadd_rn(acc, b_s[oc]);
    v32 = __fmul_rn(v32, kBNF);
    out[(oc * H + oy) * W + tx] = fmaxf(v32, 0.f);
  }
}

// ---------------------------------------------------------------- conv3x3 weight transpose: w2[(ic*9+tap)*OC+oc]
__global__ __launch_bounds__(256) void prep_w3_k(const float* __restrict__ w,
                                                 float* __restrict__ w2,
                                                 int IC, int OC) {
  int i = blockIdx.x * 256 + threadIdx.x;
  int total = IC * OC * 9;
  if (i >= total) return;
  int oc = i % OC;
  int rest = i / OC;
  int tap = rest % 9;
  int ic = rest / 9;
  w2[i] = w[((size_t)oc * IC + ic) * 9 + tap];
}

// ---------------------------------------------------------------- 3x3 conv (R9 structure, coalesced w2 staging)
template <int S, bool RELU, bool HAS_SKIP>
__global__ __launch_bounds__(256) void conv3x3_k(
    const float* __restrict__ in, const float* __restrict__ w2,
    const float* __restrict__ bias, const float* __restrict__ skip,
    float* __restrict__ out, int IC, int IH, int IW, int OC, int OH, int OW) {
  // S=1: in_f[icr][ky][68] plain cols (66 used)
  // S=2: in_f[icr][ky][136]: [0..67]=even cols, [68..135]=odd cols
  __shared__ float in_f[4][3][(S == 1) ? 68 : 136];
  __shared__ float w_f[4][9][64];
  int t = threadIdx.x;
  int ox0 = blockIdx.x * 64;
  int oy = blockIdx.y;
  int oc0 = blockIdx.z * 64;
  int oc4 = (t >> 4) * 4, px4 = (t & 15) * 4;
  float acc[4][4] = {};
  const int NCOL = 64 * S + 2;  // 66 or 130
  const int NIN = 4 * 3 * NCOL;
  for (int ic0 = 0; ic0 < IC; ic0 += 4) {
    __syncthreads();
    for (int e = t; e < NIN; e += 256) {
      int icr = e / (3 * NCOL);
      int rem = e - icr * (3 * NCOL);
      int r = rem / NCOL, c = rem - r * NCOL;
      int iy = oy * S - 1 + r;
      int ix = ox0 * S - 1 + c;
      float v = 0.f;
      if (iy >= 0 && iy < IH && ix >= 0 && ix < IW)
        v = in[((ic0 + icr) * IH + iy) * IW + ix];
      if (S == 1)
        in_f[icr][r][c] = v;
      else
        in_f[icr][r][(c & 1) * 68 + (c >> 1)] = v;
    }
    for (int e = t; e < 4 * 9 * 64; e += 256) {
      int ocr = e & 63;
      int rem = e >> 6;
      int tap = rem % 9, icr = rem / 9;
      // coalesced: consecutive lanes -> consecutive oc
      w_f[icr][tap][ocr] = w2[((size_t)(ic0 + icr) * 9 + tap) * OC + oc0 + ocr];
    }
    __syncthreads();
#pragma unroll
    for (int icr = 0; icr < 4; ++icr) {
#pragma unroll
      for (int ky = 0; ky < 3; ++ky) {
        float iv[9];
        if (S == 1) {
          float4 va = *reinterpret_cast<const float4*>(&in_f[icr][ky][px4]);
          float2 vb = *reinterpret_cast<const float2*>(&in_f[icr][ky][px4 + 4]);
          iv[0] = va.x; iv[1] = va.y; iv[2] = va.z;
          iv[3] = va.w; iv[4] = vb.x; iv[5] = vb.y;
        } else {
          float4 ve = *reinterpret_cast<const float4*>(&in_f[icr][ky][px4]);
          float se = in_f[icr][ky][px4 + 4];
          float4 vo = *reinterpret_cast<const float4*>(&in_f[icr][ky][68 + px4]);
          iv[0] = ve.x; iv[1] = ve.y; iv[2] = ve.z;
          iv[3] = ve.w; iv[4] = se;
          iv[5] = vo.x; iv[6] = vo.y; iv[7] = vo.z; iv[8] = vo.w;
        }
#pragma unroll
        for (int kx = 0; kx < 3; ++kx) {
          float4 wv = *reinterpret_cast<const float4*>(&w_f[icr][ky * 3 + kx][oc4]);
          const float* wp = (const float*)&wv;
#pragma unroll
          for (int p = 0; p < 4; ++p) {
            float ivv;
            if (S == 1) {
              ivv = iv[p + kx];
            } else {
              ivv = (kx == 0) ? iv[p] : (kx == 1) ? iv[5 + p] : iv[p + 1];
            }
#pragma unroll
            for (int o = 0; o < 4; ++o)
              acc[o][p] = fmaf(wp[o], ivv, acc[o][p]);
          }
        }
      }
    }
  }
  int opx = ox0 + px4;
  if (opx < OW) {
#pragma unroll
    for (int o = 0; o < 4; ++o) {
      int oc = oc0 + oc4 + o;
      float bv = bias[oc];
      size_t base = ((size_t)oc * OH + oy) * OW + opx;
      float4 rv;
      float* rp = (float*)&rv;
#pragma unroll
      for (int p = 0; p < 4; ++p) {
        float v32 = __fadd_rn(acc[o][p], bv);
        v32 = __fmul_rn(v32, kBNF);
        if (HAS_SKIP) v32 = __fadd_rn(v32, skip[base + p]);
        if (RELU) v32 = fmaxf(v32, 0.f);
        rp[p] = v32;
      }
      *reinterpret_cast<float4*>(&out[base]) = rv;
    }
  }
}

// ---------------------------------------------------------------- 1x1 conv, fp32 acc (R9)
template <int S, bool RELU>
__global__ __launch_bounds__(256) void conv1x1_k(
    const float* __restrict__ in, const float* __restrict__ w,
    const float* __restrict__ bias, float* __restrict__ out,
    int IC, int IH, int IW, int OC, int OH, int OW) {
  __shared__ float in_s[16][64];
  __shared__ float w_s[16][64];
  const int P = OH * OW;
  int t = threadIdx.x;
  int p0 = blockIdx.x * 64;
  int oc0 = blockIdx.y * 64;
  int oc4 = (t >> 4) * 4, px4 = (t & 15) * 4;
  float acc[4][4] = {};
  for (int ic0 = 0; ic0 < IC; ic0 += 16) {
    __syncthreads();
    {
      int e = t;
#pragma unroll
      for (int k = 0; k < 4; ++k, e += 256) {
        int icr = e >> 6, pxr = e & 63;
        int p = p0 + pxr;
        float v = 0.f;
        if (p < P) {
          int oy = p / OW, ox = p % OW;
          v = in[((ic0 + icr) * IH + oy * S) * IW + ox * S];
        }
        in_s[icr][pxr] = v;
      }
      e = t;
#pragma unroll
      for (int k = 0; k < 4; ++k, e += 256) {
        int icr = e >> 6, ocr = e & 63;
        w_s[icr][ocr] = w[(oc0 + ocr) * IC + ic0 + icr];
      }
    }
    __syncthreads();
#pragma unroll
    for (int icr = 0; icr < 16; ++icr) {
      float4 iv = *reinterpret_cast<const float4*>(&in_s[icr][px4]);
      float4 wv = *reinterpret_cast<const float4*>(&w_s[icr][oc4]);
      const float* ip = (const float*)&iv;
      const float* wp = (const float*)&wv;
#pragma unroll
      for (int o = 0; o < 4; ++o)
#pragma unroll
        for (int p = 0; p < 4; ++p)
          acc[o][p] = fmaf(wp[o], ip[p], acc[o][p]);
    }
  }
  int p = p0 + px4;
  if (p < P) {
    int oy = p / OW, ox = p % OW;
#pragma unroll
    for (int o = 0; o < 4; ++o) {
      int oc = oc0 + oc4 + o;
      float bv = bias[oc];
      float4 rv;
      float* rp = (float*)&rv;
#pragma unroll
      for (int pp = 0; pp < 4; ++pp) {
        float v32 = __fadd_rn(acc[o][pp], bv);
        v32 = __fmul_rn(v32, kBNF);
        if (RELU) v32 = fmaxf(v32, 0.f);
        rp[pp] = v32;
      }
      *reinterpret_cast<float4*>(&out[((size_t)oc * OH + oy) * OW + ox]) = rv;
    }
  }
}

// ---------------------------------------------------------------- ConvT weight transpose: w2[kyb][ic][ty][kx][OC]
__global__ __launch_bounds__(256) void prep_w2_k(const float* __restrict__ w,
                                                 float* __restrict__ w2,
                                                 int IC, int OC) {
  int i = blockIdx.x * 256 + threadIdx.x;
  int total = IC * OC * 16;
  if (i >= total) return;
  int oc = i % OC;
  int r = i / OC;
  int kx = r & 3; r >>= 2;
  int ty = r & 1; r >>= 1;
  int ic = r % IC;
  int kyb = r / IC;
  int ky = kyb + 2 * ty;
  w2[i] = w[((size_t)ic * OC + oc) * 16 + ky * 4 + kx];
}

// ---------------------------------------------------------------- ConvTranspose2d k4 s2 p1, relu, ICS=8 (R9)
__global__ __launch_bounds__(256) void convt_k(
    const float* __restrict__ in, const float* __restrict__ w2,
    const float* __restrict__ bias, float* __restrict__ out,
    int IC, int IH, int IW, int OC, int OH, int OW) {
  __shared__ float in_s[8][2][34];
  __shared__ float w_s[8][2][4][64];
  int t = threadIdx.x;
  int ox0 = blockIdx.x * 64;
  int oy = blockIdx.y;
  int oc0 = blockIdx.z * 64;
  int oc4 = (t >> 4) * 4, px4 = (t & 15) * 4;
  int kyb = (oy & 1) ? 0 : 1;
  int c0 = ox0 >> 1;
  const float* w2b = w2 + (size_t)kyb * IC * 8 * OC;  // [ic][ty][kx][OC]
  float acc[4][4] = {};
  for (int ic0 = 0; ic0 < IC; ic0 += 8) {
    __syncthreads();
    for (int e = t; e < 8 * 2 * 34; e += 256) {
      int icr = e / 68;
      int rem = e - icr * 68;
      int ty = rem / 34, cc = rem - ty * 34;
      int ky = kyb + 2 * ty;
      int iy = (oy + 1 - ky) >> 1;
      int ix = c0 - 1 + cc;
      float v = 0.f;
      if (iy >= 0 && iy < IH && ix >= 0 && ix < IW)
        v = in[((ic0 + icr) * IH + iy) * IW + ix];
      in_s[icr][ty][cc] = v;
    }
    {
      int e = t;
#pragma unroll
      for (int k = 0; k < 16; ++k, e += 256) {
        int icr = e >> 9;
        int rem = e & 511;
        int ty = rem >> 8;
        int kx = (rem >> 6) & 3;
        int ocr = rem & 63;
        w_s[icr][ty][kx][ocr] =
            w2b[((((size_t)(ic0 + icr)) * 2 + ty) * 4 + kx) * OC + oc0 + ocr];
      }
    }
    __syncthreads();
#pragma unroll
    for (int icr = 0; icr < 8; ++icr) {
      float4 wv[2][4];
#pragma unroll
      for (int ty = 0; ty < 2; ++ty)
#pragma unroll
        for (int kx = 0; kx < 4; ++kx)
          wv[ty][kx] = *reinterpret_cast<const float4*>(&w_s[icr][ty][kx][oc4]);
#pragma unroll
      for (int p = 0; p < 4; ++p) {
        int hr = (px4 + p) >> 1;
        int kxa = (p & 1) ? 0 : 1;
        int kxb = (p & 1) ? 2 : 3;
        int ca = (p & 1) ? hr + 2 : hr + 1;
        int cb2 = (p & 1) ? hr + 1 : hr;
#pragma unroll
        for (int ty = 0; ty < 2; ++ty) {
          float sa = in_s[icr][ty][ca];
          float sb = in_s[icr][ty][cb2];
          const float* wa = (const float*)&wv[ty][kxa];
          const float* wb = (const float*)&wv[ty][kxb];
#pragma unroll
          for (int o = 0; o < 4; ++o) {
            acc[o][p] = fmaf(wa[o], sa, acc[o][p]);
            acc[o][p] = fmaf(wb[o], sb, acc[o][p]);
          }
        }
      }
    }
  }
  int opx = ox0 + px4;
  if (opx < OW) {
#pragma unroll
    for (int o = 0; o < 4; ++o) {
      int oc = oc0 + oc4 + o;
      float bv = bias[oc];
      float4 rv;
      float* rp = (float*)&rv;
#pragma unroll
      for (int p = 0; p < 4; ++p) {
        float v = (acc[o][p] + bv) * kBNF;
        rp[p] = fmaxf(v, 0.f);
      }
      *reinterpret_cast<float4*>(&out[((size_t)oc * OH + oy) * OW + opx]) = rv;
    }
  }
}

// ---------------------------------------------------------------- final 3x3 conv 128->1 + sigmoid (B=1) (R9)
__global__ __launch_bounds__(320) void dow_k(const float* __restrict__ in,
                                             const float* __restrict__ w,
                                             const float* __restrict__ bias,
                                             float* __restrict__ out) {
  const int H = 320, W = 320, IC = 128;
  int oy = blockIdx.x;
  int tx = threadIdx.x;
  __shared__ float in_s[4][3][W + 2];
  __shared__ float w_s[IC * 9];
  for (int e = tx; e < IC * 9; e += 320) w_s[e] = w[e];
  float acc = 0.f;
  for (int ic0 = 0; ic0 < IC; ic0 += 4) {
    __syncthreads();
    for (int e = tx; e < 4 * 3 * (W + 2); e += 320) {
      int icr = e / (3 * (W + 2));
      int rem = e - icr * (3 * (W + 2));
      int r = rem / (W + 2), c = rem - r * (W + 2);
      int iy = oy + r - 1, ix = c - 1;
      float v = 0.f;
      if (iy >= 0 && iy < H && ix >= 0 && ix < W)
        v = in[((ic0 + icr) * H + iy) * W + ix];
      in_s[icr][r][c] = v;
    }
    __syncthreads();
#pragma unroll
    for (int icr = 0; icr < 4; ++icr)
#pragma unroll
      for (int r = 0; r < 3; ++r)
#pragma unroll
        for (int c = 0; c < 3; ++c)
          acc = fmaf(w_s[(ic0 + icr) * 9 + r * 3 + c], in_s[icr][r][tx + c], acc);
  }
  acc += bias[0];
  out[oy * W + tx] = 1.f / (1.f + expf(-acc));
}

// ---------------------------------------------------------------- codebook sq-norms: numpy-pairwise fp32
__global__ __launch_bounds__(256) void cbprep_np(const float* __restrict__ cb,
                                                 float* __restrict__ c2f) {
  int e = blockIdx.x, t = threadIdx.x;
  __shared__ float a[256];
  a[t] = cb[e * 256 + t];
  __syncthreads();
  if (t == 0) {
    float tot = 0.f;
    for (int h = 0; h < 2; ++h) {
      const float* p = a + h * 128;
      float r[8];
#pragma unroll
      for (int j = 0; j < 8; ++j) r[j] = __fmul_rn(p[j], p[j]);
      for (int i = 8; i < 128; i += 8)
#pragma unroll
        for (int j = 0; j < 8; ++j) r[j] = __fadd_rn(r[j], __fmul_rn(p[i + j], p[i + j]));
      float s = __fadd_rn(__fadd_rn(__fadd_rn(r[0], r[1]), __fadd_rn(r[2], r[3])),
                          __fadd_rn(__fadd_rn(r[4], r[5]), __fadd_rn(r[6], r[7])));
      tot = (h == 0) ? s : __fadd_rn(tot, s);
    }
    c2f[e] = tot;
  }
}

// ---------------------------------------------------------------- VQ: block-per-row, emulated fp32 ref dist (UNCHANGED)
__global__ __launch_bounds__(256) void vq_ref_k(const float* __restrict__ z,
                                                const float* __restrict__ cb,
                                                const float* __restrict__ c2f,
                                                float* __restrict__ zq_out,
                                                float* __restrict__ idx_out) {
  int row = blockIdx.x;
  int t = threadIdx.x;
  __shared__ float f[256];
  __shared__ float dist[1024];
  __shared__ float f2s;
  __shared__ int bestIdx;
  f[t] = z[(size_t)row * 256 + t];
  __syncthreads();
  if (t == 0) {
    float tot = 0.f;
    for (int h = 0; h < 2; ++h) {
      const float* p = f + h * 128;
      float r[8];
#pragma unroll
      for (int j = 0; j < 8; ++j) r[j] = __fmul_rn(p[j], p[j]);
      for (int i = 8; i < 128; i += 8)
#pragma unroll
        for (int j = 0; j < 8; ++j) r[j] = __fadd_rn(r[j], __fmul_rn(p[i + j], p[i + j]));
      float s = __fadd_rn(__fadd_rn(__fadd_rn(r[0], r[1]), __fadd_rn(r[2], r[3])),
                          __fadd_rn(__fadd_rn(r[4], r[5]), __fadd_rn(r[6], r[7])));
      tot = (h == 0) ? s : __fadd_rn(tot, s);
    }
    f2s = tot;
  }
  __syncthreads();
  float f2 = f2s;
  for (int e = t; e < 1024; e += 256) {
    const float* cbe = cb + (size_t)e * 256;
    double dot = 0.0;
    for (int d = 0; d < 256; ++d)
      dot = fma((double)f[d], (double)cbe[d], dot);
    float C = __fmul_rn(2.f, (float)dot);
    dist[e] = __fsub_rn(__fadd_rn(f2, c2f[e]), C);
  }
  __syncthreads();
  if (t == 0) {
    float bv = dist[0];
    int bi = 0;
    for (int e = 1; e < 1024; ++e)
      if (dist[e] < bv) { bv = dist[e]; bi = e; }
    bestIdx = bi;
    idx_out[row] = (float)bi;
  }
  __syncthreads();
  zq_out[(size_t)row * 256 + t] = cb[(size_t)bestIdx * 256 + t];
}

// ================================================================ host
extern "C" void kernel_launch(void* const* d_in, const int* in_sizes, int n_in,
                              void* d_out, int out_size, void* d_ws, size_t ws_size,
                              hipStream_t stream) {
  const float* x = (const float*)d_in[0];
  const float* w0 = (const float*)d_in[1];
  const float* b0 = (const float*)d_in[2];
  const float* a_c1w = (const float*)d_in[3];
  const float* a_c1b = (const float*)d_in[4];
  const float* a_c2w = (const float*)d_in[5];
  const float* a_c2b = (const float*)d_in[6];
  const float* a_scw = (const float*)d_in[7];
  const float* a_scb = (const float*)d_in[8];
  const float* b_c1w = (const float*)d_in[9];
  const float* b_c1b = (const float*)d_in[10];
  const float* b_c2w = (const float*)d_in[11];
  const float* b_c2b = (const float*)d_in[12];
  const float* b_scw = (const float*)d_in[13];
  const float* b_scb = (const float*)d_in[14];
  const float* ew = (const float*)d_in[15];
  const float* eb = (const float*)d_in[16];
  const float* cb = (const float*)d_in[17];
  const float* d0w = (const float*)d_in[18];
  const float* d0b = (const float*)d_in[19];
  const float* dt1w = (const float*)d_in[20];
  const float* dt1b = (const float*)d_in[21];
  const float* dt2w = (const float*)d_in[22];
  const float* dt2b = (const float*)d_in[23];
  const float* doww = (const float*)d_in[24];
  const float* dob = (const float*)d_in[25];

  // ws (floats): A 13.1M | B 6.55M | C 6.55M | c2f 1024  ~= 105 MB (unchanged)
  float* ws = (float*)d_ws;
  float* A = ws;
  float* Bf = ws + 13107200;
  float* Cf = ws + 19660800;
  float* c2f = ws + 26214400;
  float* w2dt1 = A;              // dead region during decoder
  float* w2dt2 = Bf + 3400000;   // past g0's 3.28M floats
  // conv3x3 transposed weights (dead-region placements, see header comment)
  float* w3_ac1 = Cf;            // 294,912 f, before a_sc overwrites Cf
  float* w3_ac2 = A + 6600000;   // 589,824 f, h0 dead; clear of a_c2 out
  float* w3_bc1 = Bf + 3300000;  // 1,179,648 f, a_c1-out dead; clear of b_c1 out
  float* w3_bc2 = A + 3300000;   // 2,359,296 f, a_out dead; clear of b_c2 out

  float* outf = (float*)d_out;
  float* recon = outf;
  float* zq = outf + 409600;
  float* idxo = zq + 6553600;

  cbprep_np<<<1024, 256, 0, stream>>>(cb, c2f);

  for (int b = 0; b < 4; ++b) {
    const float* xb = x + (size_t)b * 102400;
    float* zqb = zq + (size_t)b * 1638400;
    float* idxb = idxo + (size_t)b * 6400;
    float* reconb = recon + (size_t)b * 102400;

    // encoder (fp32; staged values + FMA order identical -> z bit-identical)
    conv0_k<<<320, 320, 0, stream>>>(xb, w0, b0, A);
    prep_w3_k<<<1152, 256, 0, stream>>>(a_c1w, w3_ac1, 128, 256);   // 294,912
    conv3x3_k<2, true, false><<<dim3(3, 160, 4), 256, 0, stream>>>(
        w3_ac1 == nullptr ? nullptr : A, w3_ac1, a_c1b, nullptr, Bf,
        128, 320, 320, 256, 160, 160);
    conv1x1_k<2, false><<<dim3(400, 4), 256, 0, stream>>>(
        A, a_scw, a_scb, Cf, 128, 320, 320, 256, 160, 160);
    prep_w3_k<<<2304, 256, 0, stream>>>(a_c2w, w3_ac2, 256, 256);   // 589,824
    conv3x3_k<1, true, true><<<dim3(3, 160, 4), 256, 0, stream>>>(
        Bf, w3_ac2, a_c2b, Cf, A, 256, 160, 160, 256, 160, 160);
    prep_w3_k<<<4608, 256, 0, stream>>>(b_c1w, w3_bc1, 256, 512);   // 1,179,648
    conv3x3_k<2, true, false><<<dim3(2, 80, 8), 256, 0, stream>>>(
        A, w3_bc1, b_c1b, nullptr, Bf, 256, 160, 160, 512, 80, 80);
    conv1x1_k<2, false><<<dim3(100, 8), 256, 0, stream>>>(
        A, b_scw, b_scb, Cf, 256, 160, 160, 512, 80, 80);
    prep_w3_k<<<9216, 256, 0, stream>>>(b_c2w, w3_bc2, 512, 512);   // 2,359,296
    conv3x3_k<1, true, true><<<dim3(2, 80, 8), 256, 0, stream>>>(
        Bf, w3_bc2, b_c2b, Cf, A, 512, 80, 80, 512, 80, 80);
    conv1x1_k<1, false><<<dim3(100, 4), 256, 0, stream>>>(
        A, ew, eb, Cf, 512, 80, 80, 256, 80, 80);
    // VQ (unchanged emulation)
    vq_ref_k<<<6400, 256, 0, stream>>>(Cf, cb, c2f, zqb, idxb);
    // decoder
    prep_w2_k<<<8192, 256, 0, stream>>>(dt1w, w2dt1, 512, 256);
    prep_w2_k<<<2048, 256, 0, stream>>>(dt2w, w2dt2, 256, 128);
    conv1x1_k<1, true><<<dim3(100, 8), 256, 0, stream>>>(
        zqb, d0w, d0b, Bf, 256, 80, 80, 512, 80, 80);
    convt_k<<<dim3(3, 160, 4), 256, 0, stream>>>(
        Bf, w2dt1, dt1b, Cf, 512, 80, 80, 256, 160, 160);
    convt_k<<<dim3(5, 320, 2), 256, 0, stream>>>(
        Cf, w2dt2, dt2b, A, 256, 160, 160, 128, 320, 320);
    dow_k<<<320, 320, 0, stream>>>(A, doww, dob, reconb);
  }
}